// Round 2
// baseline (1299.598 us; speedup 1.0000x reference)
//
#include <hip/hip_runtime.h>

typedef _Float16 hx8 __attribute__((ext_vector_type(8)));
typedef float    fx4 __attribute__((ext_vector_type(4)));

constexpr int T_ = 4608;   // tokens = 8*576
constexpr int D_ = 1024;
constexpr int H_ = 4096;
constexpr int C_ = 4096;
constexpr int E_ = 8;
constexpr int BM = 128;
constexpr int PADROWS = T_ * 2 + E_ * BM;  // 10240

// global -> LDS direct (16B/lane), dest = wave-uniform base + lane*16
__device__ __forceinline__ void gload16(const void* g, void* l) {
    __builtin_amdgcn_global_load_lds(
        (const __attribute__((address_space(1))) void*)g,
        (__attribute__((address_space(3))) void*)l, 16, 0, 0);
}

// ---------------- fp32 -> fp16 streaming convert ----------------
__global__ __launch_bounds__(256) void k_cvt(const float* __restrict__ s,
                                             _Float16* __restrict__ d, int n8)
{
    const fx4* s4 = (const fx4*)s;
    hx8* d8 = (hx8*)d;
    for (size_t i = (size_t)blockIdx.x * 256 + threadIdx.x; i < (size_t)n8;
         i += (size_t)gridDim.x * 256) {
        fx4 a = s4[2 * i], b = s4[2 * i + 1];
        hx8 h;
        h[0]=(_Float16)a[0]; h[1]=(_Float16)a[1]; h[2]=(_Float16)a[2]; h[3]=(_Float16)a[3];
        h[4]=(_Float16)b[0]; h[5]=(_Float16)b[1]; h[6]=(_Float16)b[2]; h[7]=(_Float16)b[3];
        d8[i] = h;
    }
}

// ---------------- routing: logits, top-2, softmax, x -> fp16 ----------------
__global__ __launch_bounds__(256) void k_route(
    const float* __restrict__ x, const float* __restrict__ sw,
    const float* __restrict__ sb, _Float16* __restrict__ xh,
    int* __restrict__ meta, int* __restrict__ e0a, int* __restrict__ e1a,
    float* __restrict__ w0a, float* __restrict__ w1a)
{
    __shared__ float ssw[E_ * D_];
    const int tid = threadIdx.x;
    for (int i = tid; i < E_ * D_ / 4; i += 256)
        reinterpret_cast<fx4*>(ssw)[i] = reinterpret_cast<const fx4*>(sw)[i];
    __syncthreads();

    const int wid = tid >> 6, lane = tid & 63;
    const int t = blockIdx.x * 4 + wid;
    const float* xr = x + (size_t)t * D_;
    _Float16* xhr = xh + (size_t)t * D_;

    float acc[E_] = {};
    for (int i = lane; i < D_; i += 64) {
        float xv = xr[i];
        xhr[i] = (_Float16)xv;
        #pragma unroll
        for (int e = 0; e < E_; e++) acc[e] += xv * ssw[e * D_ + i];
    }
    #pragma unroll
    for (int e = 0; e < E_; e++) {
        float v = acc[e];
        #pragma unroll
        for (int o = 32; o > 0; o >>= 1) v += __shfl_xor(v, o, 64);
        acc[e] = v;
    }
    if (lane == 0) {
        float l[E_];
        #pragma unroll
        for (int e = 0; e < E_; e++) l[e] = acc[e] + sb[e];
        int b0 = 0; float v0 = l[0];
        #pragma unroll
        for (int e = 1; e < E_; e++) if (l[e] > v0) { v0 = l[e]; b0 = e; }
        int b1 = -1; float v1 = -3.4e38f;
        #pragma unroll
        for (int e = 0; e < E_; e++) if (e != b0 && l[e] > v1) { v1 = l[e]; b1 = e; }
        float r = __expf(v1 - v0);
        float inv = 1.f / (1.f + r);
        e0a[t] = b0; e1a[t] = b1; w0a[t] = inv; w1a[t] = r * inv;
        atomicAdd(&meta[b0], 1);
        atomicAdd(&meta[b1], 1);
    }
}

__global__ void k_scan(int* meta)
{
    if (threadIdx.x == 0) {
        int off = 0;
        for (int e = 0; e < E_; e++) {
            meta[16 + e] = off;
            off += ((meta[e] + BM - 1) / BM) * BM;
        }
        meta[24] = off;
    }
}

__global__ void k_scatter(int* __restrict__ meta,
                          const int* __restrict__ e0a, const int* __restrict__ e1a,
                          const float* __restrict__ w0a, const float* __restrict__ w1a,
                          int* __restrict__ tok, float* __restrict__ gate)
{
    int t = blockIdx.x * 256 + threadIdx.x;
    if (t >= T_) return;
    int* cursors = meta + 8;
    const int* padoff = meta + 16;
    int e0 = e0a[t];
    int s0 = atomicAdd(&cursors[e0], 1);
    tok[padoff[e0] + s0] = t; gate[padoff[e0] + s0] = w0a[t];
    int e1 = e1a[t];
    int s1 = atomicAdd(&cursors[e1], 1);
    tok[padoff[e1] + s1] = t; gate[padoff[e1] + s1] = w1a[t];
}

// ================= fast path: fp16 weights, global_load_lds, swizzled LDS =================
// LDS tiles: linear [rows][64] halves (128B rows). Staged via global_load_lds with
// pre-swizzled global column; ds_read applies byte ^= ((row&7)<<4)  (here in halves: <<3).

// GEMM1: 128 rows x 64 hcols, dual-B (W1,W3), BK=64
__global__ __launch_bounds__(256) void k_gemm1_h(
    const _Float16* __restrict__ xh,
    const _Float16* __restrict__ w1h, const float* __restrict__ b1,
    const _Float16* __restrict__ w3h, const float* __restrict__ b3,
    const int* __restrict__ meta, const int* __restrict__ tok,
    _Float16* __restrict__ hbuf)
{
    const int e = blockIdx.z;
    const int n_e = meta[e];
    const int row0 = blockIdx.y * BM;
    if (row0 >= n_e) return;
    const int col0 = blockIdx.x * 64;
    const int prow0 = meta[16 + e] + row0;

    __shared__ _Float16 sA[128 * 64];
    __shared__ _Float16 sB1[64 * 64];
    __shared__ _Float16 sB3[64 * 64];

    const int tid = threadIdx.x;
    const int w = tid >> 6, l = tid & 63;
    const int lrow = l >> 3;                 // row within 8-row chunk
    const int lcolh = 8 * ((l & 7) ^ lrow);  // pre-swizzled source col (halves)

    const _Float16* aSrc[4];
    _Float16* aDst[4];
    #pragma unroll
    for (int i = 0; i < 4; i++) {
        const int c = w * 4 + i;
        const int t = tok[prow0 + c * 8 + lrow];   // pad rows -> token 0 (memset)
        aSrc[i] = xh + (size_t)t * D_ + lcolh;
        aDst[i] = &sA[c * 512];
    }
    const _Float16 *b1Src[2], *b3Src[2];
    _Float16 *b1Dst[2], *b3Dst[2];
    #pragma unroll
    for (int i = 0; i < 2; i++) {
        const int c = w * 2 + i;
        const int r = c * 8 + lrow;
        b1Src[i] = w1h + ((size_t)e * H_ + col0 + r) * D_ + lcolh;
        b3Src[i] = w3h + ((size_t)e * H_ + col0 + r) * D_ + lcolh;
        b1Dst[i] = &sB1[c * 512];
        b3Dst[i] = &sB3[c * 512];
    }

    const int wr = (w >> 1) * 64, wc = (w & 1) * 32;
    const int fr = l & 15, q = l >> 4;

    fx4 acc1[4][2] = {}, acc3[4][2] = {};

    for (int kk = 0; kk < D_; kk += 64) {
        __syncthreads();
        #pragma unroll
        for (int i = 0; i < 4; i++) gload16(aSrc[i] + kk, aDst[i]);
        #pragma unroll
        for (int i = 0; i < 2; i++) {
            gload16(b1Src[i] + kk, b1Dst[i]);
            gload16(b3Src[i] + kk, b3Dst[i]);
        }
        __syncthreads();   // drains vmcnt -> tiles ready
        #pragma unroll
        for (int ks = 0; ks < 2; ks++) {
            const int kb = ks * 32 + q * 8;
            hx8 af[4], bf1[2], bf3[2];
            #pragma unroll
            for (int mi = 0; mi < 4; mi++) {
                const int R = wr + mi * 16 + fr;
                af[mi] = *(const hx8*)&sA[R * 64 + (kb ^ ((R & 7) << 3))];
            }
            #pragma unroll
            for (int ni = 0; ni < 2; ni++) {
                const int R = wc + ni * 16 + fr;
                bf1[ni] = *(const hx8*)&sB1[R * 64 + (kb ^ ((R & 7) << 3))];
                bf3[ni] = *(const hx8*)&sB3[R * 64 + (kb ^ ((R & 7) << 3))];
            }
            #pragma unroll
            for (int ni = 0; ni < 2; ni++)
                #pragma unroll
                for (int mi = 0; mi < 4; mi++) {
                    acc1[mi][ni] = __builtin_amdgcn_mfma_f32_16x16x32_f16(af[mi], bf1[ni], acc1[mi][ni], 0, 0, 0);
                    acc3[mi][ni] = __builtin_amdgcn_mfma_f32_16x16x32_f16(af[mi], bf3[ni], acc3[mi][ni], 0, 0, 0);
                }
        }
    }

    #pragma unroll
    for (int ni = 0; ni < 2; ni++) {
        const int col = col0 + wc + ni * 16 + fr;
        const float bb1 = b1[(size_t)e * H_ + col];
        const float bb3 = b3[(size_t)e * H_ + col];
        #pragma unroll
        for (int mi = 0; mi < 4; mi++) {
            const int rbase = wr + mi * 16 + q * 4;
            #pragma unroll
            for (int j = 0; j < 4; j++) {
                const int r = rbase + j;
                if (row0 + r < n_e) {
                    float v1 = acc1[mi][ni][j] + bb1;
                    float v3 = acc3[mi][ni][j] + bb3;
                    float hv = v1 * v3 / (1.f + __expf(-v1));
                    hbuf[(size_t)(prow0 + r) * H_ + col] = (_Float16)hv;
                }
            }
        }
    }
}

// GEMM2: 128 rows x 128 cols, BK=64
__global__ __launch_bounds__(256) void k_gemm2_h(
    const _Float16* __restrict__ hbuf, const _Float16* __restrict__ w2h,
    const float* __restrict__ b2, const int* __restrict__ meta,
    const int* __restrict__ tok, const float* __restrict__ gate,
    float* __restrict__ out)
{
    const int e = blockIdx.z;
    const int n_e = meta[e];
    const int row0 = blockIdx.y * BM;
    if (row0 >= n_e) return;
    const int col0 = blockIdx.x * 128;
    const int prow0 = meta[16 + e] + row0;

    __shared__ _Float16 sA[128 * 64];
    __shared__ _Float16 sB[128 * 64];

    const int tid = threadIdx.x;
    const int w = tid >> 6, l = tid & 63;
    const int lrow = l >> 3;
    const int lcolh = 8 * ((l & 7) ^ lrow);

    const _Float16 *aSrc[4], *bSrc[4];
    _Float16 *aDst[4], *bDst[4];
    #pragma unroll
    for (int i = 0; i < 4; i++) {
        const int c = w * 4 + i;
        const int r = c * 8 + lrow;
        aSrc[i] = hbuf + (size_t)(prow0 + r) * H_ + lcolh;   // pad rows in-bounds (garbage, masked)
        bSrc[i] = w2h + ((size_t)e * C_ + col0 + r) * H_ + lcolh;
        aDst[i] = &sA[c * 512];
        bDst[i] = &sB[c * 512];
    }

    const int wr = (w >> 1) * 64, wc = (w & 1) * 64;
    const int fr = l & 15, q = l >> 4;

    fx4 acc[4][4] = {};

    for (int kk = 0; kk < H_; kk += 64) {
        __syncthreads();
        #pragma unroll
        for (int i = 0; i < 4; i++) {
            gload16(aSrc[i] + kk, aDst[i]);
            gload16(bSrc[i] + kk, bDst[i]);
        }
        __syncthreads();
        #pragma unroll
        for (int ks = 0; ks < 2; ks++) {
            const int kb = ks * 32 + q * 8;
            hx8 af[4], bf[4];
            #pragma unroll
            for (int mi = 0; mi < 4; mi++) {
                const int R = wr + mi * 16 + fr;
                af[mi] = *(const hx8*)&sA[R * 64 + (kb ^ ((R & 7) << 3))];
            }
            #pragma unroll
            for (int ni = 0; ni < 4; ni++) {
                const int R = wc + ni * 16 + fr;
                bf[ni] = *(const hx8*)&sB[R * 64 + (kb ^ ((R & 7) << 3))];
            }
            #pragma unroll
            for (int ni = 0; ni < 4; ni++)
                #pragma unroll
                for (int mi = 0; mi < 4; mi++)
                    acc[mi][ni] = __builtin_amdgcn_mfma_f32_16x16x32_f16(af[mi], bf[ni], acc[mi][ni], 0, 0, 0);
        }
    }

    #pragma unroll
    for (int ni = 0; ni < 4; ni++) {
        const int col = col0 + wc + ni * 16 + fr;
        const float bb = b2[(size_t)e * C_ + col];
        #pragma unroll
        for (int mi = 0; mi < 4; mi++) {
            const int rbase = wr + mi * 16 + q * 4;
            #pragma unroll
            for (int j = 0; j < 4; j++) {
                const int r = rbase + j;
                if (row0 + r < n_e) {
                    const int prow = prow0 + r;
                    atomicAdd(&out[(size_t)tok[prow] * C_ + col],
                              gate[prow] * (acc[mi][ni][j] + bb));
                }
            }
        }
    }
}

// ================= fallback path (round-1 proven, fp32 weights in-kernel convert) =================
__global__ __launch_bounds__(256) void k_gemm1_f(
    const _Float16* __restrict__ xh,
    const float* __restrict__ w1, const float* __restrict__ b1,
    const float* __restrict__ w3, const float* __restrict__ b3,
    const int* __restrict__ meta, const int* __restrict__ tok,
    _Float16* __restrict__ hbuf)
{
    const int e = blockIdx.z;
    const int n_e = meta[e];
    const int row0 = blockIdx.y * BM;
    if (row0 >= n_e) return;
    const int col0 = blockIdx.x * 64;
    const int prow0 = meta[16 + e] + row0;

    __shared__ _Float16 sA[128][40];
    __shared__ _Float16 sB1[64][40];
    __shared__ _Float16 sB3[64][40];

    const int tid = threadIdx.x;
    const int ar = tid >> 2, ac = (tid & 3) * 8;
    const int i0 = (row0 + ar      < n_e) ? ar      : 0;
    const int i1 = (row0 + ar + 64 < n_e) ? ar + 64 : 0;
    const int t0 = tok[prow0 + i0];
    const int t1 = tok[prow0 + i1];
    const _Float16* a0p = xh + (size_t)t0 * D_ + ac;
    const _Float16* a1p = xh + (size_t)t1 * D_ + ac;
    const int br = tid >> 2, bc = (tid & 3) * 8;
    const float* w1p = w1 + ((size_t)e * H_ + col0 + br) * D_ + bc;
    const float* w3p = w3 + ((size_t)e * H_ + col0 + br) * D_ + bc;

    const int lane = tid & 63, wid = tid >> 6;
    const int wr = (wid >> 1) * 64, wc = (wid & 1) * 32;
    const int fr = lane & 15, kg = (lane >> 4) * 8;

    fx4 acc1[4][2] = {};
    fx4 acc3[4][2] = {};

    for (int kk = 0; kk < D_; kk += 32) {
        __syncthreads();
        *(hx8*)&sA[ar][ac]      = *(const hx8*)(a0p + kk);
        *(hx8*)&sA[ar + 64][ac] = *(const hx8*)(a1p + kk);
        {
            fx4 f0 = *(const fx4*)(w1p + kk);
            fx4 f1 = *(const fx4*)(w1p + kk + 4);
            hx8 hv;
            hv[0]=(_Float16)f0[0]; hv[1]=(_Float16)f0[1]; hv[2]=(_Float16)f0[2]; hv[3]=(_Float16)f0[3];
            hv[4]=(_Float16)f1[0]; hv[5]=(_Float16)f1[1]; hv[6]=(_Float16)f1[2]; hv[7]=(_Float16)f1[3];
            *(hx8*)&sB1[br][bc] = hv;
            fx4 g0 = *(const fx4*)(w3p + kk);
            fx4 g1 = *(const fx4*)(w3p + kk + 4);
            hx8 gv;
            gv[0]=(_Float16)g0[0]; gv[1]=(_Float16)g0[1]; gv[2]=(_Float16)g0[2]; gv[3]=(_Float16)g0[3];
            gv[4]=(_Float16)g1[0]; gv[5]=(_Float16)g1[1]; gv[6]=(_Float16)g1[2]; gv[7]=(_Float16)g1[3];
            *(hx8*)&sB3[br][bc] = gv;
        }
        __syncthreads();
        hx8 af[4];
        #pragma unroll
        for (int mi = 0; mi < 4; mi++)
            af[mi] = *(const hx8*)&sA[wr + mi * 16 + fr][kg];
        #pragma unroll
        for (int ni = 0; ni < 2; ni++) {
            hx8 bf1 = *(const hx8*)&sB1[wc + ni * 16 + fr][kg];
            hx8 bf3 = *(const hx8*)&sB3[wc + ni * 16 + fr][kg];
            #pragma unroll
            for (int mi = 0; mi < 4; mi++) {
                acc1[mi][ni] = __builtin_amdgcn_mfma_f32_16x16x32_f16(af[mi], bf1, acc1[mi][ni], 0, 0, 0);
                acc3[mi][ni] = __builtin_amdgcn_mfma_f32_16x16x32_f16(af[mi], bf3, acc3[mi][ni], 0, 0, 0);
            }
        }
    }

    #pragma unroll
    for (int ni = 0; ni < 2; ni++) {
        const int col = col0 + wc + ni * 16 + fr;
        const float bb1 = b1[(size_t)e * H_ + col];
        const float bb3 = b3[(size_t)e * H_ + col];
        #pragma unroll
        for (int mi = 0; mi < 4; mi++) {
            const int rbase = wr + mi * 16 + (lane >> 4) * 4;
            #pragma unroll
            for (int j = 0; j < 4; j++) {
                const int r = rbase + j;
                if (row0 + r < n_e) {
                    float v1 = acc1[mi][ni][j] + bb1;
                    float v3 = acc3[mi][ni][j] + bb3;
                    float hv = v1 * v3 / (1.f + __expf(-v1));
                    hbuf[(size_t)(prow0 + r) * H_ + col] = (_Float16)hv;
                }
            }
        }
    }
}

__global__ __launch_bounds__(256) void k_gemm2_f(
    const _Float16* __restrict__ hbuf,
    const float* __restrict__ w2, const float* __restrict__ b2,
    const int* __restrict__ meta, const int* __restrict__ tok,
    const float* __restrict__ gate, float* __restrict__ out)
{
    const int e = blockIdx.z;
    const int n_e = meta[e];
    const int row0 = blockIdx.y * BM;
    if (row0 >= n_e) return;
    const int col0 = blockIdx.x * 128;
    const int prow0 = meta[16 + e] + row0;

    __shared__ _Float16 sA[128][40];
    __shared__ _Float16 sB[128][40];

    const int tid = threadIdx.x;
    const int ar = tid >> 2, ac = (tid & 3) * 8;
    const _Float16* a0p = hbuf + (size_t)(prow0 + ar) * H_ + ac;
    const _Float16* a1p = hbuf + (size_t)(prow0 + ar + 64) * H_ + ac;
    const int br = tid >> 2, bc = (tid & 3) * 8;
    const float* p0 = w2 + ((size_t)e * C_ + col0 + br) * H_ + bc;
    const float* p1 = w2 + ((size_t)e * C_ + col0 + br + 64) * H_ + bc;

    const int lane = tid & 63, wid = tid >> 6;
    const int wr = (wid >> 1) * 64, wc = (wid & 1) * 64;
    const int fr = lane & 15, kg = (lane >> 4) * 8;

    fx4 acc[4][4] = {};

    for (int kk = 0; kk < H_; kk += 32) {
        __syncthreads();
        *(hx8*)&sA[ar][ac]      = *(const hx8*)(a0p + kk);
        *(hx8*)&sA[ar + 64][ac] = *(const hx8*)(a1p + kk);
        {
            fx4 f0 = *(const fx4*)(p0 + kk);
            fx4 f1 = *(const fx4*)(p0 + kk + 4);
            hx8 hv;
            hv[0]=(_Float16)f0[0]; hv[1]=(_Float16)f0[1]; hv[2]=(_Float16)f0[2]; hv[3]=(_Float16)f0[3];
            hv[4]=(_Float16)f1[0]; hv[5]=(_Float16)f1[1]; hv[6]=(_Float16)f1[2]; hv[7]=(_Float16)f1[3];
            *(hx8*)&sB[br][bc] = hv;
            fx4 g0 = *(const fx4*)(p1 + kk);
            fx4 g1 = *(const fx4*)(p1 + kk + 4);
            hx8 gv;
            gv[0]=(_Float16)g0[0]; gv[1]=(_Float16)g0[1]; gv[2]=(_Float16)g0[2]; gv[3]=(_Float16)g0[3];
            gv[4]=(_Float16)g1[0]; gv[5]=(_Float16)g1[1]; gv[6]=(_Float16)g1[2]; gv[7]=(_Float16)g1[3];
            *(hx8*)&sB[br + 64][bc] = gv;
        }
        __syncthreads();
        hx8 af[4], bf[4];
        #pragma unroll
        for (int mi = 0; mi < 4; mi++)
            af[mi] = *(const hx8*)&sA[wr + mi * 16 + fr][kg];
        #pragma unroll
        for (int ni = 0; ni < 4; ni++)
            bf[ni] = *(const hx8*)&sB[wc + ni * 16 + fr][kg];
        #pragma unroll
        for (int ni = 0; ni < 4; ni++)
            #pragma unroll
            for (int mi = 0; mi < 4; mi++)
                acc[mi][ni] = __builtin_amdgcn_mfma_f32_16x16x32_f16(af[mi], bf[ni], acc[mi][ni], 0, 0, 0);
    }

    #pragma unroll
    for (int ni = 0; ni < 4; ni++) {
        const int col = col0 + wc + ni * 16 + fr;
        const float bb = b2[(size_t)e * C_ + col];
        #pragma unroll
        for (int mi = 0; mi < 4; mi++) {
            const int rbase = wr + mi * 16 + (lane >> 4) * 4;
            #pragma unroll
            for (int j = 0; j < 4; j++) {
                const int r = rbase + j;
                if (row0 + r < n_e) {
                    const int prow = prow0 + r;
                    atomicAdd(&out[(size_t)tok[prow] * C_ + col],
                              gate[prow] * (acc[mi][ni][j] + bb));
                }
            }
        }
    }
}

// ---------------- launch ----------------
extern "C" void kernel_launch(void* const* d_in, const int* in_sizes, int n_in,
                              void* d_out, int out_size, void* d_ws, size_t ws_size,
                              hipStream_t stream)
{
    const float* x  = (const float*)d_in[0];
    const float* sw = (const float*)d_in[1];
    const float* sb = (const float*)d_in[2];
    const float* w1 = (const float*)d_in[3];
    const float* b1 = (const float*)d_in[4];
    const float* w2 = (const float*)d_in[5];
    const float* b2 = (const float*)d_in[6];
    const float* w3 = (const float*)d_in[7];
    const float* b3 = (const float*)d_in[8];
    float* out = (float*)d_out;

    char* ws = (char*)d_ws;
    const size_t OFF_META = 0;
    const size_t OFF_E0   = 256;
    const size_t OFF_E1   = OFF_E0 + 4 * (size_t)T_;
    const size_t OFF_W0   = OFF_E1 + 4 * (size_t)T_;
    const size_t OFF_W1A  = OFF_W0 + 4 * (size_t)T_;
    const size_t OFF_TOK  = OFF_W1A + 4 * (size_t)T_;
    const size_t OFF_GATE = OFF_TOK + 4 * (size_t)PADROWS;
    const size_t OFF_XH   = OFF_GATE + 4 * (size_t)PADROWS;
    const size_t OFF_HBUF = OFF_XH + 2 * (size_t)T_ * D_;
    const size_t OFF_W1H  = OFF_HBUF + 2 * (size_t)PADROWS * H_;
    const size_t OFF_W3H  = OFF_W1H + 2 * (size_t)E_ * H_ * D_;
    const size_t OFF_W2H  = OFF_W3H + 2 * (size_t)E_ * H_ * D_;
    const size_t NEED     = OFF_W2H + 2 * (size_t)E_ * C_ * H_;

    int*      meta  = (int*)(ws + OFF_META);
    int*      e0a   = (int*)(ws + OFF_E0);
    int*      e1a   = (int*)(ws + OFF_E1);
    float*    w0a   = (float*)(ws + OFF_W0);
    float*    w1a   = (float*)(ws + OFF_W1A);
    int*      tokb  = (int*)(ws + OFF_TOK);
    float*    gateb = (float*)(ws + OFF_GATE);
    _Float16* xh    = (_Float16*)(ws + OFF_XH);
    _Float16* hbuf  = (_Float16*)(ws + OFF_HBUF);
    _Float16* w1h   = (_Float16*)(ws + OFF_W1H);
    _Float16* w3h   = (_Float16*)(ws + OFF_W3H);
    _Float16* w2h   = (_Float16*)(ws + OFF_W2H);

    hipMemsetAsync(d_out, 0, sizeof(float) * (size_t)T_ * C_, stream);
    hipMemsetAsync(meta, 0, 256, stream);
    hipMemsetAsync(tokb, 0, 4 * (size_t)PADROWS, stream);

    k_route<<<T_ / 4, 256, 0, stream>>>(x, sw, sb, xh, meta, e0a, e1a, w0a, w1a);
    k_scan<<<1, 1, 0, stream>>>(meta);
    k_scatter<<<(T_ + 255) / 256, 256, 0, stream>>>(meta, e0a, e1a, w0a, w1a, tokb, gateb);

    if (ws_size >= NEED) {
        k_cvt<<<2048, 256, 0, stream>>>(w1, w1h, E_ * H_ * D_ / 8);
        k_cvt<<<2048, 256, 0, stream>>>(w3, w3h, E_ * H_ * D_ / 8);
        k_cvt<<<4096, 256, 0, stream>>>(w2, w2h, E_ * C_ * H_ / 8);
        k_gemm1_h<<<dim3(H_ / 64, T_ / BM, E_), 256, 0, stream>>>(xh, w1h, b1, w3h, b3, meta, tokb, hbuf);
        k_gemm2_h<<<dim3(C_ / 128, T_ / BM, E_), 256, 0, stream>>>(hbuf, w2h, b2, meta, tokb, gateb, out);
    } else {
        k_gemm1_f<<<dim3(H_ / 64, T_ / BM, E_), 256, 0, stream>>>(xh, w1, b1, w3, b3, meta, tokb, hbuf);
        k_gemm2_f<<<dim3(C_ / 128, T_ / BM, E_), 256, 0, stream>>>(hbuf, w2, b2, meta, tokb, gateb, out);
    }
}

// Round 3
// 1156.655 us; speedup vs baseline: 1.1236x; 1.1236x over previous
//
#include <hip/hip_runtime.h>

typedef _Float16 hx8 __attribute__((ext_vector_type(8)));
typedef float    fx4 __attribute__((ext_vector_type(4)));

constexpr int T_ = 4608;   // tokens = 8*576
constexpr int D_ = 1024;
constexpr int H_ = 4096;
constexpr int C_ = 4096;
constexpr int E_ = 8;
constexpr int BM = 128;
constexpr int PADROWS = T_ * 2 + E_ * BM;  // 10240

constexpr int NB_ROUTE = T_ / 4;                    // 1152
constexpr int NB_CVT1  = 1024;                      // w1 cvt blocks
constexpr int NB_CVT3  = 1024;                      // w3 cvt blocks
constexpr int NB_A     = NB_ROUTE + NB_CVT1 + NB_CVT3;
constexpr int NB_G1    = (H_ / 64) * (T_ / BM) * E_; // 18432
constexpr int NB_CVT2  = 2048;
constexpr int NB_B     = NB_G1 + NB_CVT2;           // 20480

// global -> LDS direct (16B/lane), dest = wave-uniform base + lane*16
__device__ __forceinline__ void gload16(const void* g, void* l) {
    __builtin_amdgcn_global_load_lds(
        (const __attribute__((address_space(1))) void*)g,
        (__attribute__((address_space(3))) void*)l, 16, 0, 0);
}

// grid-strided fp32 -> fp16 convert over n8 hx8-chunks
__device__ __forceinline__ void cvt_stride(const float* __restrict__ s,
                                           _Float16* __restrict__ d,
                                           int n8, int bidx, int nblocks)
{
    const fx4* s4 = (const fx4*)s;
    hx8* d8 = (hx8*)d;
    const int stride = nblocks * 256;
    for (int i = bidx * 256 + (int)threadIdx.x; i < n8; i += stride) {
        fx4 a = s4[2 * (size_t)i], b = s4[2 * (size_t)i + 1];
        hx8 h;
        h[0]=(_Float16)a[0]; h[1]=(_Float16)a[1]; h[2]=(_Float16)a[2]; h[3]=(_Float16)a[3];
        h[4]=(_Float16)b[0]; h[5]=(_Float16)b[1]; h[6]=(_Float16)b[2]; h[7]=(_Float16)b[3];
        d8[i] = h;
    }
}

// ---------------- launch A: routing + cvt W1/W3 ----------------
__global__ __launch_bounds__(256) void k_routecvt(
    const float* __restrict__ x, const float* __restrict__ sw,
    const float* __restrict__ sb,
    const float* __restrict__ w1, _Float16* __restrict__ w1h,
    const float* __restrict__ w3, _Float16* __restrict__ w3h,
    _Float16* __restrict__ xh,
    int* __restrict__ meta, int* __restrict__ e0a, int* __restrict__ e1a,
    float* __restrict__ w0a, float* __restrict__ w1a)
{
    __shared__ float ssw[E_ * D_];
    const int id = blockIdx.x;
    const int tid = threadIdx.x;

    if (id >= NB_ROUTE) {
        if (id < NB_ROUTE + NB_CVT1)
            cvt_stride(w1, w1h, E_ * H_ * D_ / 8, id - NB_ROUTE, NB_CVT1);
        else
            cvt_stride(w3, w3h, E_ * H_ * D_ / 8, id - NB_ROUTE - NB_CVT1, NB_CVT3);
        return;
    }

    for (int i = tid; i < E_ * D_ / 4; i += 256)
        reinterpret_cast<fx4*>(ssw)[i] = reinterpret_cast<const fx4*>(sw)[i];
    __syncthreads();

    const int wid = tid >> 6, lane = tid & 63;
    const int t = id * 4 + wid;
    const float* xr = x + (size_t)t * D_;
    _Float16* xhr = xh + (size_t)t * D_;

    float acc[E_] = {};
    for (int i = lane; i < D_; i += 64) {
        float xv = xr[i];
        xhr[i] = (_Float16)xv;
        #pragma unroll
        for (int e = 0; e < E_; e++) acc[e] += xv * ssw[e * D_ + i];
    }
    #pragma unroll
    for (int e = 0; e < E_; e++) {
        float v = acc[e];
        #pragma unroll
        for (int o = 32; o > 0; o >>= 1) v += __shfl_xor(v, o, 64);
        acc[e] = v;
    }
    if (lane == 0) {
        float l[E_];
        #pragma unroll
        for (int e = 0; e < E_; e++) l[e] = acc[e] + sb[e];
        int b0 = 0; float v0 = l[0];
        #pragma unroll
        for (int e = 1; e < E_; e++) if (l[e] > v0) { v0 = l[e]; b0 = e; }
        int b1 = -1; float v1 = -3.4e38f;
        #pragma unroll
        for (int e = 0; e < E_; e++) if (e != b0 && l[e] > v1) { v1 = l[e]; b1 = e; }
        float r = __expf(v1 - v0);
        float inv = 1.f / (1.f + r);
        e0a[t] = b0; e1a[t] = b1; w0a[t] = inv; w1a[t] = r * inv;
        atomicAdd(&meta[b0], 1);
        atomicAdd(&meta[b1], 1);
    }
}

__global__ void k_scan(int* meta)
{
    if (threadIdx.x == 0) {
        int off = 0;
        for (int e = 0; e < E_; e++) {
            meta[16 + e] = off;
            off += ((meta[e] + BM - 1) / BM) * BM;
        }
        meta[24] = off;
    }
}

__global__ void k_scatter(int* __restrict__ meta,
                          const int* __restrict__ e0a, const int* __restrict__ e1a,
                          const float* __restrict__ w0a, const float* __restrict__ w1a,
                          int* __restrict__ tok, float* __restrict__ gate,
                          int* __restrict__ inv)
{
    int t = blockIdx.x * 256 + threadIdx.x;
    if (t >= T_) return;
    int* cursors = meta + 8;
    const int* padoff = meta + 16;
    int e0 = e0a[t];
    int s0 = atomicAdd(&cursors[e0], 1);
    int p0 = padoff[e0] + s0;
    tok[p0] = t; gate[p0] = w0a[t]; inv[2 * t] = p0;
    int e1 = e1a[t];
    int s1 = atomicAdd(&cursors[e1], 1);
    int p1 = padoff[e1] + s1;
    tok[p1] = t; gate[p1] = w1a[t]; inv[2 * t + 1] = p1;
}

// ---------------- launch B: GEMM1 (fp16 weights) fused with W2 cvt ----------------
__global__ __launch_bounds__(256) void k_g1cvt2(
    const _Float16* __restrict__ xh,
    const _Float16* __restrict__ w1h, const float* __restrict__ b1,
    const _Float16* __restrict__ w3h, const float* __restrict__ b3,
    const float* __restrict__ w2, _Float16* __restrict__ w2h,
    const int* __restrict__ meta, const int* __restrict__ tok,
    _Float16* __restrict__ hbuf)
{
    __shared__ _Float16 sA[128 * 64];
    __shared__ _Float16 sB1[64 * 64];
    __shared__ _Float16 sB3[64 * 64];

    const int id = blockIdx.x;
    if (id % 10 == 9) {                 // interleaved cvt blocks (2048)
        cvt_stride(w2, w2h, E_ * C_ * H_ / 8, id / 10, NB_CVT2);
        return;
    }
    const int g1 = id - id / 10;        // 0 .. NB_G1-1
    const int col = g1 & 63;
    const int rest = g1 >> 6;
    const int e = rest / 36;
    const int rowtile = rest - e * 36;

    const int n_e = meta[e];
    const int row0 = rowtile * BM;
    if (row0 >= n_e) return;
    const int col0 = col * 64;
    const int prow0 = meta[16 + e] + row0;

    const int tid = threadIdx.x;
    const int w = tid >> 6, l = tid & 63;
    const int lrow = l >> 3;
    const int lcolh = 8 * ((l & 7) ^ lrow);   // pre-swizzled source col (halves)

    const _Float16* aSrc[4];
    _Float16* aDst[4];
    #pragma unroll
    for (int i = 0; i < 4; i++) {
        const int c = w * 4 + i;
        const int t = tok[prow0 + c * 8 + lrow];   // pad rows -> token 0 (memset)
        aSrc[i] = xh + (size_t)t * D_ + lcolh;
        aDst[i] = &sA[c * 512];
    }
    const _Float16 *b1Src[2], *b3Src[2];
    _Float16 *b1Dst[2], *b3Dst[2];
    #pragma unroll
    for (int i = 0; i < 2; i++) {
        const int c = w * 2 + i;
        const int r = c * 8 + lrow;
        b1Src[i] = w1h + ((size_t)e * H_ + col0 + r) * D_ + lcolh;
        b3Src[i] = w3h + ((size_t)e * H_ + col0 + r) * D_ + lcolh;
        b1Dst[i] = &sB1[c * 512];
        b3Dst[i] = &sB3[c * 512];
    }

    const int wr = (w >> 1) * 64, wc = (w & 1) * 32;
    const int fr = l & 15, q = l >> 4;

    fx4 acc1[4][2] = {}, acc3[4][2] = {};

    for (int kk = 0; kk < D_; kk += 64) {
        __syncthreads();
        #pragma unroll
        for (int i = 0; i < 4; i++) gload16(aSrc[i] + kk, aDst[i]);
        #pragma unroll
        for (int i = 0; i < 2; i++) {
            gload16(b1Src[i] + kk, b1Dst[i]);
            gload16(b3Src[i] + kk, b3Dst[i]);
        }
        __syncthreads();
        #pragma unroll
        for (int ks = 0; ks < 2; ks++) {
            const int kb = ks * 32 + q * 8;
            hx8 af[4], bf1[2], bf3[2];
            #pragma unroll
            for (int mi = 0; mi < 4; mi++) {
                const int R = wr + mi * 16 + fr;
                af[mi] = *(const hx8*)&sA[R * 64 + (kb ^ ((R & 7) << 3))];
            }
            #pragma unroll
            for (int ni = 0; ni < 2; ni++) {
                const int R = wc + ni * 16 + fr;
                bf1[ni] = *(const hx8*)&sB1[R * 64 + (kb ^ ((R & 7) << 3))];
                bf3[ni] = *(const hx8*)&sB3[R * 64 + (kb ^ ((R & 7) << 3))];
            }
            #pragma unroll
            for (int ni = 0; ni < 2; ni++)
                #pragma unroll
                for (int mi = 0; mi < 4; mi++) {
                    acc1[mi][ni] = __builtin_amdgcn_mfma_f32_16x16x32_f16(af[mi], bf1[ni], acc1[mi][ni], 0, 0, 0);
                    acc3[mi][ni] = __builtin_amdgcn_mfma_f32_16x16x32_f16(af[mi], bf3[ni], acc3[mi][ni], 0, 0, 0);
                }
        }
    }

    #pragma unroll
    for (int ni = 0; ni < 2; ni++) {
        const int colg = col0 + wc + ni * 16 + fr;
        const float bb1 = b1[(size_t)e * H_ + colg];
        const float bb3 = b3[(size_t)e * H_ + colg];
        #pragma unroll
        for (int mi = 0; mi < 4; mi++) {
            const int rbase = wr + mi * 16 + q * 4;
            #pragma unroll
            for (int j = 0; j < 4; j++) {
                const int r = rbase + j;
                if (row0 + r < n_e) {
                    float v1 = acc1[mi][ni][j] + bb1;
                    float v3 = acc3[mi][ni][j] + bb3;
                    float hv = v1 * v3 / (1.f + __expf(-v1));
                    hbuf[(size_t)(prow0 + r) * H_ + colg] = (_Float16)hv;
                }
            }
        }
    }
}

// ---------------- GEMM2: part = h W2^T + b2 (fp16 partials, no atomics) ----------------
__global__ __launch_bounds__(256) void k_gemm2_h(
    const _Float16* __restrict__ hbuf, const _Float16* __restrict__ w2h,
    const float* __restrict__ b2, const int* __restrict__ meta,
    _Float16* __restrict__ part)
{
    const int e = blockIdx.z;
    const int n_e = meta[e];
    const int row0 = blockIdx.y * BM;
    if (row0 >= n_e) return;
    const int col0 = blockIdx.x * 128;
    const int prow0 = meta[16 + e] + row0;

    __shared__ _Float16 sA[128 * 64];
    __shared__ _Float16 sB[128 * 64];

    const int tid = threadIdx.x;
    const int w = tid >> 6, l = tid & 63;
    const int lrow = l >> 3;
    const int lcolh = 8 * ((l & 7) ^ lrow);

    const _Float16 *aSrc[4], *bSrc[4];
    _Float16 *aDst[4], *bDst[4];
    #pragma unroll
    for (int i = 0; i < 4; i++) {
        const int c = w * 4 + i;
        const int r = c * 8 + lrow;
        aSrc[i] = hbuf + (size_t)(prow0 + r) * H_ + lcolh;   // pad rows benign
        bSrc[i] = w2h + ((size_t)e * C_ + col0 + r) * H_ + lcolh;
        aDst[i] = &sA[c * 512];
        bDst[i] = &sB[c * 512];
    }

    const int wr = (w >> 1) * 64, wc = (w & 1) * 64;
    const int fr = l & 15, q = l >> 4;

    fx4 acc[4][4] = {};

    for (int kk = 0; kk < H_; kk += 64) {
        __syncthreads();
        #pragma unroll
        for (int i = 0; i < 4; i++) {
            gload16(aSrc[i] + kk, aDst[i]);
            gload16(bSrc[i] + kk, bDst[i]);
        }
        __syncthreads();
        #pragma unroll
        for (int ks = 0; ks < 2; ks++) {
            const int kb = ks * 32 + q * 8;
            hx8 af[4], bf[4];
            #pragma unroll
            for (int mi = 0; mi < 4; mi++) {
                const int R = wr + mi * 16 + fr;
                af[mi] = *(const hx8*)&sA[R * 64 + (kb ^ ((R & 7) << 3))];
            }
            #pragma unroll
            for (int ni = 0; ni < 4; ni++) {
                const int R = wc + ni * 16 + fr;
                bf[ni] = *(const hx8*)&sB[R * 64 + (kb ^ ((R & 7) << 3))];
            }
            #pragma unroll
            for (int ni = 0; ni < 4; ni++)
                #pragma unroll
                for (int mi = 0; mi < 4; mi++)
                    acc[mi][ni] = __builtin_amdgcn_mfma_f32_16x16x32_f16(af[mi], bf[ni], acc[mi][ni], 0, 0, 0);
        }
    }

    // plain fp16 stores of partials (bias added; gate applied in combine)
    #pragma unroll
    for (int ni = 0; ni < 4; ni++) {
        const int col = col0 + wc + ni * 16 + fr;
        const float bb = b2[(size_t)e * C_ + col];
        #pragma unroll
        for (int mi = 0; mi < 4; mi++) {
            const int rbase = wr + mi * 16 + q * 4;
            #pragma unroll
            for (int j = 0; j < 4; j++) {
                const int prow = prow0 + rbase + j;       // pad rows: in-bounds, never read
                part[(size_t)prow * C_ + col] = (_Float16)(acc[mi][ni][j] + bb);
            }
        }
    }
}

// ---------------- combine: out[t] = g0*part[inv0] + g1*part[inv1] ----------------
__global__ __launch_bounds__(256) void k_combine(
    const _Float16* __restrict__ part, const int* __restrict__ inv,
    const float* __restrict__ gate, float* __restrict__ out)
{
    const int bid = blockIdx.x;               // T_*2 blocks
    const int t = bid >> 1;
    const int c0 = ((bid & 1) << 11) + ((int)threadIdx.x << 3);
    const int p0 = inv[2 * t], p1 = inv[2 * t + 1];
    const float g0 = gate[p0], g1 = gate[p1];
    hx8 a = *(const hx8*)(part + (size_t)p0 * C_ + c0);
    hx8 b = *(const hx8*)(part + (size_t)p1 * C_ + c0);
    fx4 o0, o1;
    #pragma unroll
    for (int j = 0; j < 4; j++) {
        o0[j] = g0 * (float)a[j]     + g1 * (float)b[j];
        o1[j] = g0 * (float)a[4 + j] + g1 * (float)b[4 + j];
    }
    *(fx4*)(out + (size_t)t * C_ + c0)     = o0;
    *(fx4*)(out + (size_t)t * C_ + c0 + 4) = o1;
}

// ================= fallback path (round-1 proven, fp32 weights, atomics) =================
__global__ __launch_bounds__(256) void k_route_fb(
    const float* __restrict__ x, const float* __restrict__ sw,
    const float* __restrict__ sb, _Float16* __restrict__ xh,
    int* __restrict__ meta, int* __restrict__ e0a, int* __restrict__ e1a,
    float* __restrict__ w0a, float* __restrict__ w1a)
{
    __shared__ float ssw[E_ * D_];
    const int tid = threadIdx.x;
    for (int i = tid; i < E_ * D_ / 4; i += 256)
        reinterpret_cast<fx4*>(ssw)[i] = reinterpret_cast<const fx4*>(sw)[i];
    __syncthreads();
    const int wid = tid >> 6, lane = tid & 63;
    const int t = blockIdx.x * 4 + wid;
    const float* xr = x + (size_t)t * D_;
    _Float16* xhr = xh + (size_t)t * D_;
    float acc[E_] = {};
    for (int i = lane; i < D_; i += 64) {
        float xv = xr[i];
        xhr[i] = (_Float16)xv;
        #pragma unroll
        for (int e = 0; e < E_; e++) acc[e] += xv * ssw[e * D_ + i];
    }
    #pragma unroll
    for (int e = 0; e < E_; e++) {
        float v = acc[e];
        #pragma unroll
        for (int o = 32; o > 0; o >>= 1) v += __shfl_xor(v, o, 64);
        acc[e] = v;
    }
    if (lane == 0) {
        float l[E_];
        #pragma unroll
        for (int e = 0; e < E_; e++) l[e] = acc[e] + sb[e];
        int b0 = 0; float v0 = l[0];
        #pragma unroll
        for (int e = 1; e < E_; e++) if (l[e] > v0) { v0 = l[e]; b0 = e; }
        int b1 = -1; float v1 = -3.4e38f;
        #pragma unroll
        for (int e = 0; e < E_; e++) if (e != b0 && l[e] > v1) { v1 = l[e]; b1 = e; }
        float r = __expf(v1 - v0);
        float inv = 1.f / (1.f + r);
        e0a[t] = b0; e1a[t] = b1; w0a[t] = inv; w1a[t] = r * inv;
        atomicAdd(&meta[b0], 1);
        atomicAdd(&meta[b1], 1);
    }
}

__global__ __launch_bounds__(256) void k_gemm1_f(
    const _Float16* __restrict__ xh,
    const float* __restrict__ w1, const float* __restrict__ b1,
    const float* __restrict__ w3, const float* __restrict__ b3,
    const int* __restrict__ meta, const int* __restrict__ tok,
    _Float16* __restrict__ hbuf)
{
    const int e = blockIdx.z;
    const int n_e = meta[e];
    const int row0 = blockIdx.y * BM;
    if (row0 >= n_e) return;
    const int col0 = blockIdx.x * 64;
    const int prow0 = meta[16 + e] + row0;
    __shared__ _Float16 sA[128][40];
    __shared__ _Float16 sB1[64][40];
    __shared__ _Float16 sB3[64][40];
    const int tid = threadIdx.x;
    const int ar = tid >> 2, ac = (tid & 3) * 8;
    const int i0 = (row0 + ar      < n_e) ? ar      : 0;
    const int i1 = (row0 + ar + 64 < n_e) ? ar + 64 : 0;
    const int t0 = tok[prow0 + i0];
    const int t1 = tok[prow0 + i1];
    const _Float16* a0p = xh + (size_t)t0 * D_ + ac;
    const _Float16* a1p = xh + (size_t)t1 * D_ + ac;
    const int br = tid >> 2, bc = (tid & 3) * 8;
    const float* w1p = w1 + ((size_t)e * H_ + col0 + br) * D_ + bc;
    const float* w3p = w3 + ((size_t)e * H_ + col0 + br) * D_ + bc;
    const int lane = tid & 63, wid = tid >> 6;
    const int wr = (wid >> 1) * 64, wc = (wid & 1) * 32;
    const int fr = lane & 15, kg = (lane >> 4) * 8;
    fx4 acc1[4][2] = {};
    fx4 acc3[4][2] = {};
    for (int kk = 0; kk < D_; kk += 32) {
        __syncthreads();
        *(hx8*)&sA[ar][ac]      = *(const hx8*)(a0p + kk);
        *(hx8*)&sA[ar + 64][ac] = *(const hx8*)(a1p + kk);
        {
            fx4 f0 = *(const fx4*)(w1p + kk);
            fx4 f1 = *(const fx4*)(w1p + kk + 4);
            hx8 hv;
            hv[0]=(_Float16)f0[0]; hv[1]=(_Float16)f0[1]; hv[2]=(_Float16)f0[2]; hv[3]=(_Float16)f0[3];
            hv[4]=(_Float16)f1[0]; hv[5]=(_Float16)f1[1]; hv[6]=(_Float16)f1[2]; hv[7]=(_Float16)f1[3];
            *(hx8*)&sB1[br][bc] = hv;
            fx4 g0 = *(const fx4*)(w3p + kk);
            fx4 g1 = *(const fx4*)(w3p + kk + 4);
            hx8 gv;
            gv[0]=(_Float16)g0[0]; gv[1]=(_Float16)g0[1]; gv[2]=(_Float16)g0[2]; gv[3]=(_Float16)g0[3];
            gv[4]=(_Float16)g1[0]; gv[5]=(_Float16)g1[1]; gv[6]=(_Float16)g1[2]; gv[7]=(_Float16)g1[3];
            *(hx8*)&sB3[br][bc] = gv;
        }
        __syncthreads();
        hx8 af[4];
        #pragma unroll
        for (int mi = 0; mi < 4; mi++)
            af[mi] = *(const hx8*)&sA[wr + mi * 16 + fr][kg];
        #pragma unroll
        for (int ni = 0; ni < 2; ni++) {
            hx8 bf1 = *(const hx8*)&sB1[wc + ni * 16 + fr][kg];
            hx8 bf3 = *(const hx8*)&sB3[wc + ni * 16 + fr][kg];
            #pragma unroll
            for (int mi = 0; mi < 4; mi++) {
                acc1[mi][ni] = __builtin_amdgcn_mfma_f32_16x16x32_f16(af[mi], bf1, acc1[mi][ni], 0, 0, 0);
                acc3[mi][ni] = __builtin_amdgcn_mfma_f32_16x16x32_f16(af[mi], bf3, acc3[mi][ni], 0, 0, 0);
            }
        }
    }
    #pragma unroll
    for (int ni = 0; ni < 2; ni++) {
        const int col = col0 + wc + ni * 16 + fr;
        const float bb1 = b1[(size_t)e * H_ + col];
        const float bb3 = b3[(size_t)e * H_ + col];
        #pragma unroll
        for (int mi = 0; mi < 4; mi++) {
            const int rbase = wr + mi * 16 + (lane >> 4) * 4;
            #pragma unroll
            for (int j = 0; j < 4; j++) {
                const int r = rbase + j;
                if (row0 + r < n_e) {
                    float v1 = acc1[mi][ni][j] + bb1;
                    float v3 = acc3[mi][ni][j] + bb3;
                    float hv = v1 * v3 / (1.f + __expf(-v1));
                    hbuf[(size_t)(prow0 + r) * H_ + col] = (_Float16)hv;
                }
            }
        }
    }
}

__global__ __launch_bounds__(256) void k_gemm2_f(
    const _Float16* __restrict__ hbuf,
    const float* __restrict__ w2, const float* __restrict__ b2,
    const int* __restrict__ meta, const int* __restrict__ tok,
    const float* __restrict__ gate, float* __restrict__ out)
{
    const int e = blockIdx.z;
    const int n_e = meta[e];
    const int row0 = blockIdx.y * BM;
    if (row0 >= n_e) return;
    const int col0 = blockIdx.x * 128;
    const int prow0 = meta[16 + e] + row0;
    __shared__ _Float16 sA[128][40];
    __shared__ _Float16 sB[128][40];
    const int tid = threadIdx.x;
    const int ar = tid >> 2, ac = (tid & 3) * 8;
    const _Float16* a0p = hbuf + (size_t)(prow0 + ar) * H_ + ac;
    const _Float16* a1p = hbuf + (size_t)(prow0 + ar + 64) * H_ + ac;
    const int br = tid >> 2, bc = (tid & 3) * 8;
    const float* p0 = w2 + ((size_t)e * C_ + col0 + br) * H_ + bc;
    const float* p1 = w2 + ((size_t)e * C_ + col0 + br + 64) * H_ + bc;
    const int lane = tid & 63, wid = tid >> 6;
    const int wr = (wid >> 1) * 64, wc = (wid & 1) * 64;
    const int fr = lane & 15, kg = (lane >> 4) * 8;
    fx4 acc[4][4] = {};
    for (int kk = 0; kk < H_; kk += 32) {
        __syncthreads();
        *(hx8*)&sA[ar][ac]      = *(const hx8*)(a0p + kk);
        *(hx8*)&sA[ar + 64][ac] = *(const hx8*)(a1p + kk);
        {
            fx4 f0 = *(const fx4*)(p0 + kk);
            fx4 f1 = *(const fx4*)(p0 + kk + 4);
            hx8 hv;
            hv[0]=(_Float16)f0[0]; hv[1]=(_Float16)f0[1]; hv[2]=(_Float16)f0[2]; hv[3]=(_Float16)f0[3];
            hv[4]=(_Float16)f1[0]; hv[5]=(_Float16)f1[1]; hv[6]=(_Float16)f1[2]; hv[7]=(_Float16)f1[3];
            *(hx8*)&sB[br][bc] = hv;
            fx4 g0 = *(const fx4*)(p1 + kk);
            fx4 g1 = *(const fx4*)(p1 + kk + 4);
            hx8 gv;
            gv[0]=(_Float16)g0[0]; gv[1]=(_Float16)g0[1]; gv[2]=(_Float16)g0[2]; gv[3]=(_Float16)g0[3];
            gv[4]=(_Float16)g1[0]; gv[5]=(_Float16)g1[1]; gv[6]=(_Float16)g1[2]; gv[7]=(_Float16)g1[3];
            *(hx8*)&sB[br + 64][bc] = gv;
        }
        __syncthreads();
        hx8 af[4], bf[4];
        #pragma unroll
        for (int mi = 0; mi < 4; mi++)
            af[mi] = *(const hx8*)&sA[wr + mi * 16 + fr][kg];
        #pragma unroll
        for (int ni = 0; ni < 4; ni++)
            bf[ni] = *(const hx8*)&sB[wc + ni * 16 + fr][kg];
        #pragma unroll
        for (int ni = 0; ni < 4; ni++)
            #pragma unroll
            for (int mi = 0; mi < 4; mi++)
                acc[mi][ni] = __builtin_amdgcn_mfma_f32_16x16x32_f16(af[mi], bf[ni], acc[mi][ni], 0, 0, 0);
    }
    #pragma unroll
    for (int ni = 0; ni < 4; ni++) {
        const int col = col0 + wc + ni * 16 + fr;
        const float bb = b2[(size_t)e * C_ + col];
        #pragma unroll
        for (int mi = 0; mi < 4; mi++) {
            const int rbase = wr + mi * 16 + (lane >> 4) * 4;
            #pragma unroll
            for (int j = 0; j < 4; j++) {
                const int r = rbase + j;
                if (row0 + r < n_e) {
                    const int prow = prow0 + r;
                    atomicAdd(&out[(size_t)tok[prow] * C_ + col],
                              gate[prow] * (acc[mi][ni][j] + bb));
                }
            }
        }
    }
}

// ---------------- launch ----------------
extern "C" void kernel_launch(void* const* d_in, const int* in_sizes, int n_in,
                              void* d_out, int out_size, void* d_ws, size_t ws_size,
                              hipStream_t stream)
{
    const float* x  = (const float*)d_in[0];
    const float* sw = (const float*)d_in[1];
    const float* sb = (const float*)d_in[2];
    const float* w1 = (const float*)d_in[3];
    const float* b1 = (const float*)d_in[4];
    const float* w2 = (const float*)d_in[5];
    const float* b2 = (const float*)d_in[6];
    const float* w3 = (const float*)d_in[7];
    const float* b3 = (const float*)d_in[8];
    float* out = (float*)d_out;

    char* ws = (char*)d_ws;
    const size_t OFF_META = 0;
    const size_t OFF_E0   = 256;
    const size_t OFF_E1   = OFF_E0 + 4 * (size_t)T_;
    const size_t OFF_W0   = OFF_E1 + 4 * (size_t)T_;
    const size_t OFF_W1A  = OFF_W0 + 4 * (size_t)T_;
    const size_t OFF_TOK  = OFF_W1A + 4 * (size_t)T_;
    const size_t OFF_GATE = OFF_TOK + 4 * (size_t)PADROWS;
    const size_t OFF_INV  = OFF_GATE + 4 * (size_t)PADROWS;
    const size_t OFF_XH   = OFF_INV + 8 * (size_t)T_;
    const size_t OFF_HBUF = OFF_XH + 2 * (size_t)T_ * D_;
    const size_t OFF_PART = OFF_HBUF + 2 * (size_t)PADROWS * H_;
    const size_t OFF_W1H  = OFF_PART + 2 * (size_t)PADROWS * C_;
    const size_t OFF_W3H  = OFF_W1H + 2 * (size_t)E_ * H_ * D_;
    const size_t OFF_W2H  = OFF_W3H + 2 * (size_t)E_ * H_ * D_;
    const size_t NEED     = OFF_W2H + 2 * (size_t)E_ * C_ * H_;

    int*      meta  = (int*)(ws + OFF_META);
    int*      e0a   = (int*)(ws + OFF_E0);
    int*      e1a   = (int*)(ws + OFF_E1);
    float*    w0a   = (float*)(ws + OFF_W0);
    float*    w1a   = (float*)(ws + OFF_W1A);
    int*      tokb  = (int*)(ws + OFF_TOK);
    float*    gateb = (float*)(ws + OFF_GATE);
    int*      invb  = (int*)(ws + OFF_INV);
    _Float16* xh    = (_Float16*)(ws + OFF_XH);
    _Float16* hbuf  = (_Float16*)(ws + OFF_HBUF);
    _Float16* partb = (_Float16*)(ws + OFF_PART);
    _Float16* w1h   = (_Float16*)(ws + OFF_W1H);
    _Float16* w3h   = (_Float16*)(ws + OFF_W3H);
    _Float16* w2h   = (_Float16*)(ws + OFF_W2H);

    hipMemsetAsync(meta, 0, 256, stream);
    hipMemsetAsync(tokb, 0, 4 * (size_t)PADROWS, stream);

    if (ws_size >= NEED) {
        k_routecvt<<<NB_A, 256, 0, stream>>>(x, sw, sb, w1, w1h, w3, w3h, xh,
                                             meta, e0a, e1a, w0a, w1a);
        k_scan<<<1, 1, 0, stream>>>(meta);
        k_scatter<<<(T_ + 255) / 256, 256, 0, stream>>>(meta, e0a, e1a, w0a, w1a,
                                                        tokb, gateb, invb);
        k_g1cvt2<<<NB_B, 256, 0, stream>>>(xh, w1h, b1, w3h, b3, w2, w2h,
                                           meta, tokb, hbuf);
        k_gemm2_h<<<dim3(C_ / 128, T_ / BM, E_), 256, 0, stream>>>(hbuf, w2h, b2,
                                                                   meta, partb);
        k_combine<<<T_ * 2, 256, 0, stream>>>(partb, invb, gateb, out);
    } else {
        hipMemsetAsync(d_out, 0, sizeof(float) * (size_t)T_ * C_, stream);
        k_route_fb<<<T_ / 4, 256, 0, stream>>>(x, sw, sb, xh, meta, e0a, e1a, w0a, w1a);
        k_scan<<<1, 1, 0, stream>>>(meta);
        k_scatter<<<(T_ + 255) / 256, 256, 0, stream>>>(meta, e0a, e1a, w0a, w1a,
                                                        tokb, gateb, invb);
        k_gemm1_f<<<dim3(H_ / 64, T_ / BM, E_), 256, 0, stream>>>(xh, w1, b1, w3, b3,
                                                                  meta, tokb, hbuf);
        k_gemm2_f<<<dim3(C_ / 128, T_ / BM, E_), 256, 0, stream>>>(hbuf, w2, b2, meta,
                                                                   tokb, gateb, out);
    }
}